// Round 1
// baseline (255.320 us; speedup 1.0000x reference)
//
#include <hip/hip_runtime.h>

// Problem constants (from reference setup_inputs)
constexpr int B   = 65536;
constexpr int C   = 2;
constexpr int P   = 41;
constexpr int L   = 4;
constexpr int PL  = P * L;        // 164 elements per (b, c)
constexpr int CPL = C * PL;       // 328 floats of logits per batch
constexpr int NTH = B * P;        // one thread per (b, p): 2,686,976
constexpr float INV_N = 1.0f / (float)(B * P * L);   // mean over 10,747,904
constexpr float CW = 0.001f;      // connectivity weight
// GAMMA = 1.0 -> alpha = 1.0, beta = 0.5

__global__ __launch_bounds__(256)
void lace_loss_kernel(const float* __restrict__ logits,
                      const int*   __restrict__ targets,
                      float*       __restrict__ out)
{
    int t = blockIdx.x * 256 + threadIdx.x;
    float sum = 0.0f;

    if (t < NTH) {
        int b = t / P;
        int p = t - b * P;

        // float4 index: logits flat idx = b*CPL + c*PL + p*4 + l
        const float4* lg4 = (const float4*)logits;
        const int4*   tg4 = (const int4*)targets;

        int f4 = b * (CPL / 4) + p;        // c = 0 row, this p, l=0..3
        int t4 = t;                        // b*(PL/4) + p == b*41 + p == t

        float4 a0 = lg4[f4];               // logits[b,0,p,:]
        float4 a1 = lg4[f4 + PL / 4];      // logits[b,1,p,:]
        int4   tc = tg4[t4];               // targets[b,p,:]

        bool hm1 = (p >= 1), hp1 = (p <= P - 2);
        bool hm2 = (p >= 2), hp2 = (p <= P - 3);

        int4 tm1 = {0,0,0,0}, tp1 = {0,0,0,0}, tm2 = {0,0,0,0}, tp2 = {0,0,0,0};
        float4 b0 = {0,0,0,0}, b1 = {0,0,0,0};  // logits at p-1 (for pred[p-1])
        if (hm1) { tm1 = tg4[t4 - 1]; b0 = lg4[f4 - 1]; b1 = lg4[f4 + PL/4 - 1]; }
        if (hp1) { tp1 = tg4[t4 + 1]; }
        if (hm2) { tm2 = tg4[t4 - 2]; }
        if (hp2) { tp2 = tg4[t4 + 2]; }

        const float* pa0 = (const float*)&a0;
        const float* pa1 = (const float*)&a1;
        const float* pb0 = (const float*)&b0;
        const float* pb1 = (const float*)&b1;
        const int* ptc  = (const int*)&tc;
        const int* ptm1 = (const int*)&tm1;
        const int* ptp1 = (const int*)&tp1;
        const int* ptm2 = (const int*)&tm2;
        const int* ptp2 = (const int*)&tp2;

        #pragma unroll
        for (int l = 0; l < 4; ++l) {
            float l0 = pa0[l], l1 = pa1[l];
            // C=2 log-softmax: lse = max + log1p(exp(-|d|))
            float mx  = fmaxf(l0, l1);
            float lse = mx + log1pf(__expf(-fabsf(l0 - l1)));
            int   tg  = ptc[l];
            float lt  = tg ? l1 : l0;
            float loss = lse - lt;

            // boundary weights: alpha=1, beta=0.5, targets in {0,1}
            float w = 1.0f;
            if (hm1) w += fabsf((float)(tg - ptm1[l]));
            if (hp1) w += fabsf((float)(ptp1[l] - tg));
            if (hm2) w += 0.5f * fabsf((float)(tg - ptm2[l]));
            if (hp2) w += 0.5f * fabsf((float)(ptp2[l] - tg));

            float acc = loss * w;

            // connectivity: pred[p] != pred[p-1], pred = argmax -> (l1 > l0)
            if (hm1) {
                bool pred  = (l1 > l0);
                bool predm = (pb1[l] > pb0[l]);
                if (pred != predm) acc += CW;
            }
            sum += acc;
        }
    }

    // wave(64) shuffle reduction
    #pragma unroll
    for (int off = 32; off > 0; off >>= 1)
        sum += __shfl_down(sum, off, 64);

    __shared__ float wsum[4];
    int lane = threadIdx.x & 63;
    int wid  = threadIdx.x >> 6;
    if (lane == 0) wsum[wid] = sum;
    __syncthreads();
    if (threadIdx.x == 0) {
        float s = wsum[0] + wsum[1] + wsum[2] + wsum[3];
        atomicAdd(out, s * INV_N);
    }
}

extern "C" void kernel_launch(void* const* d_in, const int* in_sizes, int n_in,
                              void* d_out, int out_size, void* d_ws, size_t ws_size,
                              hipStream_t stream) {
    const float* logits  = (const float*)d_in[0];
    const int*   targets = (const int*)d_in[1];
    float* out = (float*)d_out;

    // d_out is re-poisoned before every timed launch -> zero it ourselves
    hipMemsetAsync(d_out, 0, sizeof(float), stream);

    int blocks = (NTH + 255) / 256;  // 10496
    lace_loss_kernel<<<blocks, 256, 0, stream>>>(logits, targets, out);
}

// Round 2
// 157.023 us; speedup vs baseline: 1.6260x; 1.6260x over previous
//
#include <hip/hip_runtime.h>

// Problem constants (from reference setup_inputs)
constexpr int B   = 65536;
constexpr int C   = 2;
constexpr int P   = 41;
constexpr int L   = 4;
constexpr int PL  = P * L;        // 164 elements per (b, c)
constexpr int CPL = C * PL;       // 328 floats of logits per batch
constexpr int NTH = B * P;        // one thread per (b, p): 2,686,976
constexpr int NB  = (NTH + 255) / 256;   // 10,496 blocks
constexpr float INV_N = 1.0f / (float)(B * P * L);   // mean over 10,747,904
constexpr float CW = 0.001f;      // connectivity weight
// GAMMA = 1.0 -> alpha = 1.0, beta = 0.5

__global__ __launch_bounds__(256)
void lace_partial_kernel(const float* __restrict__ logits,
                         const int*   __restrict__ targets,
                         float*       __restrict__ partial)
{
    int t = blockIdx.x * 256 + threadIdx.x;
    float sum = 0.0f;

    if (t < NTH) {
        int b = t / P;
        int p = t - b * P;

        // float4 index: logits flat idx = b*CPL + c*PL + p*4 + l
        const float4* lg4 = (const float4*)logits;
        const int4*   tg4 = (const int4*)targets;

        int f4 = b * (CPL / 4) + p;        // c = 0 row, this p, l=0..3
        int t4 = t;                        // b*(PL/4) + p == b*41 + p == t

        float4 a0 = lg4[f4];               // logits[b,0,p,:]
        float4 a1 = lg4[f4 + PL / 4];      // logits[b,1,p,:]
        int4   tc = tg4[t4];               // targets[b,p,:]

        bool hm1 = (p >= 1), hp1 = (p <= P - 2);
        bool hm2 = (p >= 2), hp2 = (p <= P - 3);

        int4 tm1 = {0,0,0,0}, tp1 = {0,0,0,0}, tm2 = {0,0,0,0}, tp2 = {0,0,0,0};
        float4 b0 = {0,0,0,0}, b1 = {0,0,0,0};  // logits at p-1 (for pred[p-1])
        if (hm1) { tm1 = tg4[t4 - 1]; b0 = lg4[f4 - 1]; b1 = lg4[f4 + PL/4 - 1]; }
        if (hp1) { tp1 = tg4[t4 + 1]; }
        if (hm2) { tm2 = tg4[t4 - 2]; }
        if (hp2) { tp2 = tg4[t4 + 2]; }

        const float* pa0 = (const float*)&a0;
        const float* pa1 = (const float*)&a1;
        const float* pb0 = (const float*)&b0;
        const float* pb1 = (const float*)&b1;
        const int* ptc  = (const int*)&tc;
        const int* ptm1 = (const int*)&tm1;
        const int* ptp1 = (const int*)&tp1;
        const int* ptm2 = (const int*)&tm2;
        const int* ptp2 = (const int*)&tp2;

        #pragma unroll
        for (int l = 0; l < 4; ++l) {
            float l0 = pa0[l], l1 = pa1[l];
            // C=2 log-softmax: lse = max + log(1 + exp(-|d|))
            float mx  = fmaxf(l0, l1);
            float e   = __expf(-fabsf(l0 - l1));
            float lse = mx + __logf(1.0f + e);
            int   tg  = ptc[l];
            float lt  = tg ? l1 : l0;
            float loss = lse - lt;

            // boundary weights: alpha=1, beta=0.5, targets in {0,1}
            float w = 1.0f;
            if (hm1) w += fabsf((float)(tg - ptm1[l]));
            if (hp1) w += fabsf((float)(ptp1[l] - tg));
            if (hm2) w += 0.5f * fabsf((float)(tg - ptm2[l]));
            if (hp2) w += 0.5f * fabsf((float)(ptp2[l] - tg));

            float acc = loss * w;

            // connectivity: pred[p] != pred[p-1], pred = argmax -> (l1 > l0)
            if (hm1) {
                bool pred  = (l1 > l0);
                bool predm = (pb1[l] > pb0[l]);
                if (pred != predm) acc += CW;
            }
            sum += acc;
        }
    }

    // wave(64) shuffle reduction
    #pragma unroll
    for (int off = 32; off > 0; off >>= 1)
        sum += __shfl_down(sum, off, 64);

    __shared__ float wsum[4];
    int lane = threadIdx.x & 63;
    int wid  = threadIdx.x >> 6;
    if (lane == 0) wsum[wid] = sum;
    __syncthreads();
    if (threadIdx.x == 0) {
        partial[blockIdx.x] = wsum[0] + wsum[1] + wsum[2] + wsum[3];
    }
}

__global__ __launch_bounds__(1024)
void lace_reduce_kernel(const float* __restrict__ partial,
                        float*       __restrict__ out)
{
    float s = 0.0f;
    for (int i = threadIdx.x; i < NB; i += 1024)
        s += partial[i];

    #pragma unroll
    for (int off = 32; off > 0; off >>= 1)
        s += __shfl_down(s, off, 64);

    __shared__ float wsum[16];
    int lane = threadIdx.x & 63;
    int wid  = threadIdx.x >> 6;
    if (lane == 0) wsum[wid] = s;
    __syncthreads();
    if (threadIdx.x == 0) {
        float total = 0.0f;
        #pragma unroll
        for (int i = 0; i < 16; ++i) total += wsum[i];
        out[0] = total * INV_N;
    }
}

extern "C" void kernel_launch(void* const* d_in, const int* in_sizes, int n_in,
                              void* d_out, int out_size, void* d_ws, size_t ws_size,
                              hipStream_t stream) {
    const float* logits  = (const float*)d_in[0];
    const int*   targets = (const int*)d_in[1];
    float* out     = (float*)d_out;
    float* partial = (float*)d_ws;   // 10,496 floats = 42 KB

    lace_partial_kernel<<<NB, 256, 0, stream>>>(logits, targets, partial);
    lace_reduce_kernel<<<1, 1024, 0, stream>>>(partial, out);
}